// Round 4
// baseline (436.995 us; speedup 1.0000x reference)
//
#include <hip/hip_runtime.h>
#include <math.h>

#define B_TOT 1024
#define T_LEN 4096
#define K_TAGS 16
#define START_TAG 14
#define STOP_TAG 15

#define LOG2E 1.4426950408889634f
#define LN2 0.6931471805599453f

#define CH 64                 // timesteps per staged chunk
#define NCH (T_LEN / CH)      // 64 chunks total
#define NCHH (NCH / 2)        // 32 chunks per half
#define ROWW 1032             // padded words per batch-row per buffer (64*16 + 8)
#define FBW (4 * ROWW)        // words per buffer (4 batch rows)
#define FBTOT 9728            // per-wave LDS floats: 128 slack + 2*FBW + 160 slack + pad

// workspace layout (float indices)
#define WS_VF 0               // [1024*16] forward half-vectors
#define WS_VB 16384           // [1024*16] backward half-vectors
#define WS_GF 32768           // [1024] gold partial, forward (+boundary)
#define WS_GB 33792           // [1024] gold partial, backward
#define WS_CF 34816           // [1024] int: forward log2 scale
#define WS_CB 35840           // [1024] int: backward log2 scale

typedef __attribute__((address_space(1))) const void GVoid;
typedef __attribute__((address_space(3))) void LVoid;

// Fused-DPP matvec step, forward:  s = (M s) * ef ; also produces next step's
// ef (efn = 2^(fn*log2e + nc)) off the serial chain. Hazard discipline: the
// first DPP reads %s two instructions after block entry; %s itself was written
// at the END of the previous block => >=2 wait-state slots guaranteed.
#define MATVEC_FWD(SV, EFV, EFNV, FNV, NEGCV, ET)                                     \
  do {                                                                                \
    float a0_, a1_, a2_, a3_, efa_, efn_;                                             \
    asm("v_mul_f32 %[a0], %[s], %[e0]\n\t"                                            \
        "v_fma_f32 %[efa], %[fn], %[l2e], %[nc]\n\t"                                  \
        "v_mul_f32_dpp %[a1], %[s], %[e1] row_ror:1 row_mask:0xf bank_mask:0xf\n\t"   \
        "v_mul_f32_dpp %[a2], %[s], %[e2] row_ror:2 row_mask:0xf bank_mask:0xf\n\t"   \
        "v_mul_f32_dpp %[a3], %[s], %[e3] row_ror:3 row_mask:0xf bank_mask:0xf\n\t"   \
        "v_fmac_f32_dpp %[a0], %[s], %[e4] row_ror:4 row_mask:0xf bank_mask:0xf\n\t"  \
        "v_fmac_f32_dpp %[a1], %[s], %[e5] row_ror:5 row_mask:0xf bank_mask:0xf\n\t"  \
        "v_fmac_f32_dpp %[a2], %[s], %[e6] row_ror:6 row_mask:0xf bank_mask:0xf\n\t"  \
        "v_fmac_f32_dpp %[a3], %[s], %[e7] row_ror:7 row_mask:0xf bank_mask:0xf\n\t"  \
        "v_fmac_f32_dpp %[a0], %[s], %[e8] row_ror:8 row_mask:0xf bank_mask:0xf\n\t"  \
        "v_fmac_f32_dpp %[a1], %[s], %[e9] row_ror:9 row_mask:0xf bank_mask:0xf\n\t"  \
        "v_fmac_f32_dpp %[a2], %[s], %[e10] row_ror:10 row_mask:0xf bank_mask:0xf\n\t"\
        "v_fmac_f32_dpp %[a3], %[s], %[e11] row_ror:11 row_mask:0xf bank_mask:0xf\n\t"\
        "v_fmac_f32_dpp %[a0], %[s], %[e12] row_ror:12 row_mask:0xf bank_mask:0xf\n\t"\
        "v_fmac_f32_dpp %[a1], %[s], %[e13] row_ror:13 row_mask:0xf bank_mask:0xf\n\t"\
        "v_fmac_f32_dpp %[a2], %[s], %[e14] row_ror:14 row_mask:0xf bank_mask:0xf\n\t"\
        "v_fmac_f32_dpp %[a3], %[s], %[e15] row_ror:15 row_mask:0xf bank_mask:0xf\n\t"\
        "v_exp_f32 %[efn], %[efa]\n\t"                                                \
        "v_add_f32 %[a0], %[a0], %[a1]\n\t"                                           \
        "v_add_f32 %[a2], %[a2], %[a3]\n\t"                                           \
        "v_add_f32 %[a0], %[a0], %[a2]\n\t"                                           \
        "v_mul_f32 %[s], %[a0], %[ef]"                                                \
        : [s] "+v"(SV), [a0] "=&v"(a0_), [a1] "=&v"(a1_), [a2] "=&v"(a2_),            \
          [a3] "=&v"(a3_), [efa] "=&v"(efa_), [efn] "=&v"(efn_)                       \
        : [ef] "v"(EFV), [fn] "v"(FNV), [l2e] "v"(LOG2E), [nc] "v"(NEGCV),            \
          [e0] "v"(ET[0]), [e1] "v"(ET[1]), [e2] "v"(ET[2]), [e3] "v"(ET[3]),         \
          [e4] "v"(ET[4]), [e5] "v"(ET[5]), [e6] "v"(ET[6]), [e7] "v"(ET[7]),         \
          [e8] "v"(ET[8]), [e9] "v"(ET[9]), [e10] "v"(ET[10]), [e11] "v"(ET[11]),     \
          [e12] "v"(ET[12]), [e13] "v"(ET[13]), [e14] "v"(ET[14]), [e15] "v"(ET[15]));\
    EFNV = efn_;                                                                      \
  } while (0)

// Backward (transposed) step:  s = M^T (s * ef).  us written at slot 0, first
// DPP reads it at slot 3 => 2 intervening instructions (hazard-safe).
#define MATVEC_BWD(SV, EFV, EFNV, FNV, NEGCV, ET)                                     \
  do {                                                                                \
    float a0_, a1_, a2_, a3_, efa_, efn_, us_;                                        \
    asm("v_mul_f32 %[us], %[s], %[ef]\n\t"                                            \
        "v_fma_f32 %[efa], %[fn], %[l2e], %[nc]\n\t"                                  \
        "v_mul_f32 %[a0], %[us], %[e0]\n\t"                                           \
        "v_mul_f32_dpp %[a1], %[us], %[e1] row_ror:1 row_mask:0xf bank_mask:0xf\n\t"  \
        "v_mul_f32_dpp %[a2], %[us], %[e2] row_ror:2 row_mask:0xf bank_mask:0xf\n\t"  \
        "v_mul_f32_dpp %[a3], %[us], %[e3] row_ror:3 row_mask:0xf bank_mask:0xf\n\t"  \
        "v_fmac_f32_dpp %[a0], %[us], %[e4] row_ror:4 row_mask:0xf bank_mask:0xf\n\t" \
        "v_fmac_f32_dpp %[a1], %[us], %[e5] row_ror:5 row_mask:0xf bank_mask:0xf\n\t" \
        "v_fmac_f32_dpp %[a2], %[us], %[e6] row_ror:6 row_mask:0xf bank_mask:0xf\n\t" \
        "v_fmac_f32_dpp %[a3], %[us], %[e7] row_ror:7 row_mask:0xf bank_mask:0xf\n\t" \
        "v_fmac_f32_dpp %[a0], %[us], %[e8] row_ror:8 row_mask:0xf bank_mask:0xf\n\t" \
        "v_fmac_f32_dpp %[a1], %[us], %[e9] row_ror:9 row_mask:0xf bank_mask:0xf\n\t" \
        "v_fmac_f32_dpp %[a2], %[us], %[e10] row_ror:10 row_mask:0xf bank_mask:0xf\n\t"\
        "v_fmac_f32_dpp %[a3], %[us], %[e11] row_ror:11 row_mask:0xf bank_mask:0xf\n\t"\
        "v_fmac_f32_dpp %[a0], %[us], %[e12] row_ror:12 row_mask:0xf bank_mask:0xf\n\t"\
        "v_fmac_f32_dpp %[a1], %[us], %[e13] row_ror:13 row_mask:0xf bank_mask:0xf\n\t"\
        "v_fmac_f32_dpp %[a2], %[us], %[e14] row_ror:14 row_mask:0xf bank_mask:0xf\n\t"\
        "v_fmac_f32_dpp %[a3], %[us], %[e15] row_ror:15 row_mask:0xf bank_mask:0xf\n\t"\
        "v_exp_f32 %[efn], %[efa]\n\t"                                                \
        "v_add_f32 %[a0], %[a0], %[a1]\n\t"                                           \
        "v_add_f32 %[a2], %[a2], %[a3]\n\t"                                           \
        "v_add_f32 %[s], %[a0], %[a2]"                                                \
        : [s] "+v"(SV), [us] "=&v"(us_), [a0] "=&v"(a0_), [a1] "=&v"(a1_),            \
          [a2] "=&v"(a2_), [a3] "=&v"(a3_), [efa] "=&v"(efa_), [efn] "=&v"(efn_)      \
        : [ef] "v"(EFV), [fn] "v"(FNV), [l2e] "v"(LOG2E), [nc] "v"(NEGCV),            \
          [e0] "v"(ET[0]), [e1] "v"(ET[1]), [e2] "v"(ET[2]), [e3] "v"(ET[3]),         \
          [e4] "v"(ET[4]), [e5] "v"(ET[5]), [e6] "v"(ET[6]), [e7] "v"(ET[7]),         \
          [e8] "v"(ET[8]), [e9] "v"(ET[9]), [e10] "v"(ET[10]), [e11] "v"(ET[11]),     \
          [e12] "v"(ET[12]), [e13] "v"(ET[13]), [e14] "v"(ET[14]), [e15] "v"(ET[15]));\
    EFNV = efn_;                                                                      \
  } while (0)

// Bidirectional bilinear split: result = log( r^T A2 A1 e_START ), r = exp(trans[STOP,:]).
// ONE 128-thread block per batch-group: wave 0 (SIMD0) = forward half,
// wave 1 (SIMD1) = backward half. 1-wave blocks all start on SIMD0, so the
// previous 2-blocks/CU layout serialized both waves on one issue port; the
// 2-wave block spreads them across SIMDs by the round-robin wave placement.
__global__ __launch_bounds__(128, 1) void crf_half_kernel(
        const float* __restrict__ feats,
        const int* __restrict__ tags,
        const float* __restrict__ trans,
        float* __restrict__ ws) {
    __shared__ float FBraw[2][FBTOT];      // per-wave feat buffers (+slack both ends)
    __shared__ int TG[2][2][4 * CH];       // per-wave tag buffers
    __shared__ float TlS[K_TAGS * K_TAGS]; // raw transitions (shared read-only)
    __shared__ int edgeRow[2][4];          // per-wave gold chain carry

    const int tid = threadIdx.x;
    const int wid = tid >> 6;              // 0 = forward wave, 1 = backward wave
    const int lane = tid & 63;
    const int r = lane >> 4;
    const int j = lane & 15;
    const int half = wid;
    const int bbase = blockIdx.x * 4;

    float* const FB = &FBraw[wid][128];    // 128-word leading slack (bwd ring underrun)

    for (int i = tid; i < K_TAGS * K_TAGS; i += 128) TlS[i] = trans[i];
    if (lane < 4) edgeRow[wid][lane] = half ? STOP_TAG : START_TAG;
    __syncthreads();

    // --- DPP direction probe: after row_ror:1, lane j holds value from lane (j+d)&15 ---
    const int pv = __builtin_amdgcn_mov_dpp(j, 0x121, 0xF, 0xF, false);
    const int d = (pv - j) & 15;  // 1 or 15

    // et[i] pairs with row_ror:i: rotated vector delivers x[(j + d*i)&15].
    float et[K_TAGS];
#pragma unroll
    for (int i = 0; i < K_TAGS; ++i) {
        const int src = (j + d * i) & 15;
        et[i] = exp2f(TlS[half ? (src * K_TAGS + j) : (j * K_TAGS + src)] * LOG2E);
    }

    const int rowbase = (lane & ~15) << 2;  // byte index of lane r*16 (bpermute, per-wave)

    auto stage = [&](int c, int pb) {
        const int t0 = c * CH;
#pragma unroll
        for (int i = 0; i < 16; ++i) {
            const int row = i >> 2, seg = i & 3;
            const float* g = feats + ((size_t)(bbase + row) * T_LEN + t0) * K_TAGS
                             + seg * 256 + lane * 4;
            const float* l = &FB[pb * FBW + row * ROWW + seg * 256];
            __builtin_amdgcn_global_load_lds((GVoid*)g, (LVoid*)l, 16, 0, 0);
        }
#pragma unroll
        for (int row = 0; row < 4; ++row) {
            const int* g = tags + (size_t)(bbase + row) * T_LEN + t0 + lane;
            const int* l = &TG[wid][pb][row * CH];
            __builtin_amdgcn_global_load_lds((GVoid*)g, (LVoid*)l, 4, 0, 0);
        }
    };

    float s = half ? exp2f(TlS[STOP_TAG * K_TAGS + j] * LOG2E)
                   : ((j == START_TAG) ? 1.0f : 0.0f);
    int Cacc = 0;        // accumulated log2 scale (exact int)
    float bp = 1.0f;     // row-reference (lane 0 of row), captured every 8th step
    float ef = 1.0f;     // current step's emission factor (pipelined one step ahead)
    float gold = 0.0f;

    if (!half) {
        // ===================== FORWARD WAVE: chunks 0..31 =====================
        stage(0, 0);
        for (int c = 0; c < NCHH; ++c) {
            const int pb = c & 1;
            if (c + 1 < NCHH) {
                stage(c + 1, pb ^ 1);
                __builtin_amdgcn_s_waitcnt(0x4F74);  // vmcnt<=20
            } else {
                __builtin_amdgcn_s_waitcnt(0x0F70);  // vmcnt(0)
            }
            __builtin_amdgcn_sched_barrier(0);

            const float* fp = &FB[pb * FBW + r * ROWW + j];
            float fr[8];
#pragma unroll
            for (int u = 0; u < 8; ++u) fr[u] = fp[u * 16];
            ef = exp2f(fmaf(fr[0], LOG2E, -4.0f));  // prime this chunk's first ef

            for (int tb = 0; tb < CH; tb += 8) {
                const float* fq = fp + (tb + 8) * 16;  // refill base (overrun -> slack)
#pragma unroll
                for (int u = 0; u < 8; ++u) {
                    const float fn = fr[(u + 1) & 7];  // next step's feat (u==7 -> refilled fr[0])
                    fr[u] = fq[u * 16];

                    float negc;
                    if (u == 6) {
                        // prep u==7's rescale from bp captured 7 steps ago
                        const int kprev = (((__float_as_int(bp) >> 23) & 0xFF) - 127);
                        Cacc += 32 + kprev;
                        negc = -(4.0f + (float)kprev);
                    } else {
                        negc = -4.0f;
                    }

                    float efn;
                    MATVEC_FWD(s, ef, efn, fn, negc, et);
                    ef = efn;

                    if (u == 7)
                        bp = __int_as_float(__builtin_amdgcn_ds_bpermute(
                                rowbase, __float_as_int(s)));
                }
            }

            // gold sidecar: transitions ENTERING t; lane j owns [4j, 4j+4)
            {
                const int* tg = &TG[wid][pb][r * CH];
                const int t4 = j * 4;
                const int pidx = (j == 0) ? 0 : (t4 - 1);
                const int pval = tg[pidx];
                int prev = (j == 0) ? edgeRow[wid][r] : pval;
                const float* fbase = &FB[pb * FBW + r * ROWW];
#pragma unroll
                for (int q = 0; q < 4; ++q) {
                    const int tc = tg[t4 + q];
                    gold += TlS[tc * K_TAGS + prev];
                    gold += fbase[(t4 + q) * 16 + tc];
                    prev = tc;
                }
                if (j == 15) edgeRow[wid][r] = prev;  // ends as tags[2047]
            }
        }
    } else {
        // ===================== BACKWARD WAVE: chunks 63..32 =====================
        stage(NCH - 1, 0);
        for (int ii = 0; ii < NCHH; ++ii) {
            const int pb = ii & 1;
            if (ii + 1 < NCHH) {
                stage(NCH - 2 - ii, pb ^ 1);
                __builtin_amdgcn_s_waitcnt(0x4F74);  // vmcnt<=20
            } else {
                __builtin_amdgcn_s_waitcnt(0x0F70);  // vmcnt(0)
            }
            __builtin_amdgcn_sched_barrier(0);

            const float* fp = &FB[pb * FBW + r * ROWW + j];
            float fr[8];
#pragma unroll
            for (int u = 0; u < 8; ++u) fr[u] = fp[(CH - 1 - u) * 16];
            ef = exp2f(fmaf(fr[0], LOG2E, -4.0f));  // prime

            for (int tb = 0; tb < CH; tb += 8) {
                const float* fq = fp + (CH - 9 - tb) * 16;  // fr[u] <- t_loc 55-tb-u (underrun -> slack)
#pragma unroll
                for (int u = 0; u < 8; ++u) {
                    const float fn = fr[(u + 1) & 7];
                    fr[u] = fq[-(u * 16)];

                    float negc;
                    if (u == 6) {
                        const int kprev = (((__float_as_int(bp) >> 23) & 0xFF) - 127);
                        Cacc += 32 + kprev;
                        negc = -(4.0f + (float)kprev);
                    } else {
                        negc = -4.0f;
                    }

                    float efn;
                    MATVEC_BWD(s, ef, efn, fn, negc, et);
                    ef = efn;

                    if (u == 7)
                        bp = __int_as_float(__builtin_amdgcn_ds_bpermute(
                                rowbase, __float_as_int(s)));
                }
            }

            // gold sidecar: transitions LEAVING t, next carried (chunks descending)
            {
                const int* tg = &TG[wid][pb][r * CH];
                const int t4 = j * 4;
                const float* fbase = &FB[pb * FBW + r * ROWW];
                const int nlast = (j == 15) ? edgeRow[wid][r] : tg[t4 + 4];
#pragma unroll
                for (int q = 0; q < 4; ++q) {
                    const int tc = tg[t4 + q];
                    const int tn = (q == 3) ? nlast : tg[t4 + q + 1];
                    gold += TlS[tn * K_TAGS + tc];
                    gold += fbase[(t4 + q) * 16 + tc];
                }
                if (j == 0) edgeRow[wid][r] = tg[0];  // ends as tags[2048]
            }
        }
    }

    // ---- epilogue: reduce gold over the 16-lane row, dump half-state to workspace ----
    float gg = gold;
#pragma unroll
    for (int dd = 1; dd < 16; dd <<= 1) gg += __shfl_xor(gg, dd, 16);

    const int b = bbase + r;
    if (!half) {
        ws[WS_VF + b * 16 + j] = s;
        if (j == 0) {
            ((int*)ws)[WS_CF + b] = Cacc;
            const int tn = tags[(size_t)b * T_LEN + (T_LEN / 2)];
            ws[WS_GF + b] = gg + TlS[tn * K_TAGS + edgeRow[wid][r]];
        }
    } else {
        ws[WS_VB + b * 16 + j] = s;
        if (j == 0) {
            ((int*)ws)[WS_CB + b] = Cacc;
            ws[WS_GB + b] = gg;
        }
    }
}

__global__ __launch_bounds__(64) void crf_combine(
        const float* __restrict__ ws, float* __restrict__ out) {
    const int b = blockIdx.x * 64 + threadIdx.x;
    const float* vf = ws + WS_VF + b * 16;
    const float* vb = ws + WS_VB + b * 16;
    float dot = 0.0f;
#pragma unroll
    for (int t = 0; t < 16; ++t) dot = fmaf(vf[t], vb[t], dot);
    const int cf = ((const int*)ws)[WS_CF + b];
    const int cb = ((const int*)ws)[WS_CB + b];
    const float g = ws[WS_GF + b] + ws[WS_GB + b];
    out[b] = LN2 * (log2f(dot) + (float)(cf + cb)) - g;
}

extern "C" void kernel_launch(void* const* d_in, const int* in_sizes, int n_in,
                              void* d_out, int out_size, void* d_ws, size_t ws_size,
                              hipStream_t stream) {
    const float* feats = (const float*)d_in[0];
    const int* tags = (const int*)d_in[1];
    const float* trans = (const float*)d_in[2];
    float* out = (float*)d_out;
    float* ws = (float*)d_ws;

    crf_half_kernel<<<dim3(B_TOT / 4), dim3(128), 0, stream>>>(feats, tags, trans, ws);
    crf_combine<<<dim3(B_TOT / 64), dim3(64), 0, stream>>>(ws, out);
}

// Round 5
// 417.252 us; speedup vs baseline: 1.0473x; 1.0473x over previous
//
#include <hip/hip_runtime.h>
#include <math.h>

#define B_TOT 1024
#define T_LEN 4096
#define K_TAGS 16
#define START_TAG 14
#define STOP_TAG 15

#define LOG2E 1.4426950408889634f
#define LN2 0.6931471805599453f

#define CH 64                 // timesteps per staged chunk
#define NCH (T_LEN / CH)      // 64 chunks total
#define NCHH (NCH / 2)        // 32 chunks per half
#define ROWW 1032             // padded words per batch-row per buffer (64*16 + 8)
#define FBW2 (2 * ROWW)       // words per buffer (2 batch rows per wave)
#define FBTOT 5120            // per-wave LDS floats (4 waves -> 80KB, forces 1 block/CU)

// workspace layout (float indices)
#define WS_VF 0               // [1024*16] forward half-vectors
#define WS_VB 16384           // [1024*16] backward half-vectors
#define WS_GF 32768           // [1024] gold partial, forward (+boundary)
#define WS_GB 33792           // [1024] gold partial, backward
#define WS_CF 34816           // [1024] int: forward log2 scale
#define WS_CB 35840           // [1024] int: backward log2 scale

typedef __attribute__((address_space(1))) const void GVoid;
typedef __attribute__((address_space(3))) void LVoid;
typedef unsigned u32x2 __attribute__((ext_vector_type(2)));

// 8-term half-matvec, forward. lo rows (0,1) accumulate output j over source
// offsets 0..7; hi rows (2,3, state pre-rotated by 8) accumulate output j over
// offsets 8..15. Shared DPP instructions serve both. efa for the next step's
// emission factor is computed off the serial chain (also the DPP hazard filler:
// first DPP reads %s >=2 instructions after the previous write of s).
#define MATVEC8_FWD(SV, PARTV, EFAV, FNV, NEGCV, ET)                                  \
  do {                                                                               \
    float a0_, a1_, a2_, a3_;                                                        \
    asm("v_mul_f32 %[a0], %[s], %[e0]\n\t"                                           \
        "v_fma_f32 %[efa], %[fn], %[l2e], %[nc]\n\t"                                 \
        "v_mul_f32_dpp %[a1], %[s], %[e1] row_ror:1 row_mask:0xf bank_mask:0xf\n\t"  \
        "v_mul_f32_dpp %[a2], %[s], %[e2] row_ror:2 row_mask:0xf bank_mask:0xf\n\t"  \
        "v_mul_f32_dpp %[a3], %[s], %[e3] row_ror:3 row_mask:0xf bank_mask:0xf\n\t"  \
        "v_fmac_f32_dpp %[a0], %[s], %[e4] row_ror:4 row_mask:0xf bank_mask:0xf\n\t" \
        "v_fmac_f32_dpp %[a1], %[s], %[e5] row_ror:5 row_mask:0xf bank_mask:0xf\n\t" \
        "v_fmac_f32_dpp %[a2], %[s], %[e6] row_ror:6 row_mask:0xf bank_mask:0xf\n\t" \
        "v_fmac_f32_dpp %[a3], %[s], %[e7] row_ror:7 row_mask:0xf bank_mask:0xf\n\t" \
        "v_add_f32 %[a0], %[a0], %[a1]\n\t"                                          \
        "v_add_f32 %[a2], %[a2], %[a3]\n\t"                                          \
        "v_add_f32 %[part], %[a0], %[a2]"                                            \
        : [part] "=&v"(PARTV), [efa] "=&v"(EFAV), [a0] "=&v"(a0_),                   \
          [a1] "=&v"(a1_), [a2] "=&v"(a2_), [a3] "=&v"(a3_)                          \
        : [s] "v"(SV), [fn] "v"(FNV), [l2e] "v"(LOG2E), [nc] "v"(NEGCV),             \
          [e0] "v"(ET[0]), [e1] "v"(ET[1]), [e2] "v"(ET[2]), [e3] "v"(ET[3]),        \
          [e4] "v"(ET[4]), [e5] "v"(ET[5]), [e6] "v"(ET[6]), [e7] "v"(ET[7]));       \
  } while (0)

// Backward (transposed): us = s*ef first, then the 8-term half-matvec.
// us written at slot 0; first DPP reads it at slot 3 (2 intervening instrs).
#define MATVEC8_BWD(SV, EFV, PARTV, EFAV, FNV, NEGCV, ET)                            \
  do {                                                                               \
    float a0_, a1_, a2_, a3_, us_;                                                   \
    asm("v_mul_f32 %[us], %[s], %[ef]\n\t"                                           \
        "v_fma_f32 %[efa], %[fn], %[l2e], %[nc]\n\t"                                 \
        "v_mul_f32 %[a0], %[us], %[e0]\n\t"                                          \
        "v_mul_f32_dpp %[a1], %[us], %[e1] row_ror:1 row_mask:0xf bank_mask:0xf\n\t" \
        "v_mul_f32_dpp %[a2], %[us], %[e2] row_ror:2 row_mask:0xf bank_mask:0xf\n\t" \
        "v_mul_f32_dpp %[a3], %[us], %[e3] row_ror:3 row_mask:0xf bank_mask:0xf\n\t" \
        "v_fmac_f32_dpp %[a0], %[us], %[e4] row_ror:4 row_mask:0xf bank_mask:0xf\n\t"\
        "v_fmac_f32_dpp %[a1], %[us], %[e5] row_ror:5 row_mask:0xf bank_mask:0xf\n\t"\
        "v_fmac_f32_dpp %[a2], %[us], %[e6] row_ror:6 row_mask:0xf bank_mask:0xf\n\t"\
        "v_fmac_f32_dpp %[a3], %[us], %[e7] row_ror:7 row_mask:0xf bank_mask:0xf\n\t"\
        "v_add_f32 %[a0], %[a0], %[a1]\n\t"                                          \
        "v_add_f32 %[a2], %[a2], %[a3]\n\t"                                          \
        "v_add_f32 %[part], %[a0], %[a2]"                                            \
        : [part] "=&v"(PARTV), [efa] "=&v"(EFAV), [us] "=&v"(us_),                   \
          [a0] "=&v"(a0_), [a1] "=&v"(a1_), [a2] "=&v"(a2_), [a3] "=&v"(a3_)         \
        : [s] "v"(SV), [ef] "v"(EFV), [fn] "v"(FNV), [l2e] "v"(LOG2E),               \
          [nc] "v"(NEGCV),                                                           \
          [e0] "v"(ET[0]), [e1] "v"(ET[1]), [e2] "v"(ET[2]), [e3] "v"(ET[3]),        \
          [e4] "v"(ET[4]), [e5] "v"(ET[5]), [e6] "v"(ET[6]), [e7] "v"(ET[7]));       \
  } while (0)

// lane^32 exchange-and-add: both plausible permlane32_swap half-swap semantics
// yield {x[j], x[j^32]} across the two outputs at every lane, so the sum is
// convention-independent.
__device__ __forceinline__ float xadd32(float x) {
    u32x2 t = __builtin_amdgcn_permlane32_swap(__float_as_uint(x), __float_as_uint(x),
                                               false, false);
    return __uint_as_float(t.x) + __uint_as_float(t.y);
}

// Bidirectional bilinear split: result = log( r^T A2 A1 e_START ).
// 256-thread block = 4 waves on SIMDs 0..3: wave0 fwd(b0,b1), wave1 bwd(b0,b1),
// wave2 fwd(b2,b3), wave3 bwd(b2,b3). Each wave: 2 batches x 32 lanes
// (lo copy rows 0,1 = s[j]; hi copy rows 2,3 = s[(j+8)&15]) -> 8 DPP terms
// per step instead of 16, combined via permlane32_swap.
__global__ __launch_bounds__(256, 1) void crf_half_kernel(
        const float* __restrict__ feats,
        const int* __restrict__ tags,
        const float* __restrict__ trans,
        float* __restrict__ ws) {
    __shared__ float FBraw[4][FBTOT];      // per-wave feat buffers (+slack both ends)
    __shared__ int TG[4][2][2 * CH];       // per-wave tag buffers (2 rows)
    __shared__ float TlS[K_TAGS * K_TAGS]; // raw transitions (shared read-only)
    __shared__ int edgeRow[4][2];          // per-wave, per-batch gold chain carry

    const int tid = threadIdx.x;
    const int wid = tid >> 6;              // wave 0..3
    const int lane = tid & 63;
    const int r = lane >> 4;               // row 0..3
    const int j = lane & 15;
    const int half = wid & 1;              // 0 = forward, 1 = backward
    const int bpair = blockIdx.x * 4 + (wid >> 1) * 2;
    const int rb = r & 1;                  // batch within pair
    const int cp = r >> 1;                 // 0 = lo copy, 1 = hi copy (pre-rotated 8)
    const int b = bpair + rb;

    float* const FB = &FBraw[wid][128];    // 128-word leading slack (bwd ring underrun)

    for (int i = tid; i < K_TAGS * K_TAGS; i += 256) TlS[i] = trans[i];
    if (lane < 2) edgeRow[wid][lane] = half ? STOP_TAG : START_TAG;
    __syncthreads();

    // --- DPP direction probe: after row_ror:1, lane j holds value from lane (j+d)&15 ---
    const int pv = __builtin_amdgcn_mov_dpp(j, 0x121, 0xF, 0xF, false);
    const int d = (pv - j) & 15;  // 1 or 15

    // et[i] pairs with row_ror:i. Local state is s[(j + 8*cp)&15]; rotation i
    // delivers s[(j + d*i + 8*cp)&15]. fwd coeff = E[j, src]; bwd = E[src, j].
    float et[8];
#pragma unroll
    for (int i = 0; i < 8; ++i) {
        const int src = (j + d * i + cp * 8) & 15;
        et[i] = exp2f(TlS[half ? (src * K_TAGS + j) : (j * K_TAGS + src)] * LOG2E);
    }

    const int colj = (j + cp * 8) & 15;    // this lane's feat column
    const int rowbase = rb << 6;           // bpermute byte addr of batch's lo lane 0

    auto stage = [&](int c, int pb) {
        const int t0 = c * CH;
#pragma unroll
        for (int i = 0; i < 8; ++i) {
            const int row = i >> 2, seg = i & 3;
            const float* g = feats + ((size_t)(bpair + row) * T_LEN + t0) * K_TAGS
                             + seg * 256 + lane * 4;
            const float* l = &FB[pb * FBW2 + row * ROWW + seg * 256];
            __builtin_amdgcn_global_load_lds((GVoid*)g, (LVoid*)l, 16, 0, 0);
        }
#pragma unroll
        for (int row = 0; row < 2; ++row) {
            const int* g = tags + (size_t)(bpair + row) * T_LEN + t0 + lane;
            const int* l = &TG[wid][pb][row * CH];
            __builtin_amdgcn_global_load_lds((GVoid*)g, (LVoid*)l, 4, 0, 0);
        }
    };

    // initial state (hi copy = pre-rotated by 8 -> use colj everywhere)
    float s = half ? exp2f(TlS[STOP_TAG * K_TAGS + colj] * LOG2E)
                   : ((colj == START_TAG) ? 1.0f : 0.0f);
    int Cacc = 0;        // accumulated log2 scale (exact int)
    float bp = 1.0f;     // batch reference (lo lane 0), captured every 8th step
    float ef = 1.0f;     // current step's emission factor (pipelined one step ahead)
    float gold = 0.0f;

    if (!half) {
        // ===================== FORWARD WAVE: chunks 0..31 =====================
        stage(0, 0);
        for (int c = 0; c < NCHH; ++c) {
            const int pb = c & 1;
            if (c + 1 < NCHH) {
                stage(c + 1, pb ^ 1);
                __builtin_amdgcn_s_waitcnt(0x0F7A);  // vmcnt<=10
            } else {
                __builtin_amdgcn_s_waitcnt(0x0F70);  // vmcnt(0)
            }
            __builtin_amdgcn_sched_barrier(0);

            const float* fp = &FB[pb * FBW2 + rb * ROWW + colj];
            float fr[8];
#pragma unroll
            for (int u = 0; u < 8; ++u) fr[u] = fp[u * 16];
            ef = exp2f(fmaf(fr[0], LOG2E, -4.0f));  // prime this chunk's first ef

            for (int tb = 0; tb < CH; tb += 8) {
                const float* fq = fp + (tb + 8) * 16;  // refill base (overrun -> slack)
#pragma unroll
                for (int u = 0; u < 8; ++u) {
                    const float fn = fr[(u + 1) & 7];  // next step's feat
                    fr[u] = fq[u * 16];

                    float negc;
                    if (u == 6) {
                        // prep u==7's rescale from bp captured 7 steps ago
                        const int kprev = (((__float_as_int(bp) >> 23) & 0xFF) - 127);
                        Cacc += 32 + kprev;
                        negc = -(4.0f + (float)kprev);
                    } else {
                        negc = -4.0f;
                    }

                    float part, efa;
                    MATVEC8_FWD(s, part, efa, fn, negc, et);
                    const float sum = xadd32(part);  // lo+hi partials -> full matvec

                    // lo rows: s = sum[j]*ef[j]; hi rows: s = sum[j+8]*ef[j+8]
                    // (hi ef register already holds ef[(j+8)] via colj stream)
                    float snew, efn;
                    asm("v_mul_f32 %[sv], %[sum], %[ef]\n\t"
                        "v_exp_f32 %[efn], %[efa]\n\t"
                        "v_mul_f32_dpp %[sv], %[sum], %[ef] row_ror:8 row_mask:0xc bank_mask:0xf"
                        : [sv] "=&v"(snew), [efn] "=&v"(efn)
                        : [sum] "v"(sum), [ef] "v"(ef), [efa] "v"(efa));
                    s = snew;
                    ef = efn;

                    if (u == 7)
                        bp = __int_as_float(__builtin_amdgcn_ds_bpermute(
                                rowbase, __float_as_int(s)));
                }
            }

            // gold sidecar: transitions ENTERING t; lane j owns [4j, 4j+4).
            // rows 0/2 and 1/3 duplicate their batch's work (benign).
            {
                const int* tg = &TG[wid][pb][rb * CH];
                const int t4 = j * 4;
                const int pidx = (j == 0) ? 0 : (t4 - 1);
                const int pval = tg[pidx];
                int prev = (j == 0) ? edgeRow[wid][rb] : pval;
                const float* fbase = &FB[pb * FBW2 + rb * ROWW];
#pragma unroll
                for (int q = 0; q < 4; ++q) {
                    const int tc = tg[t4 + q];
                    gold += TlS[tc * K_TAGS + prev];
                    gold += fbase[(t4 + q) * 16 + tc];
                    prev = tc;
                }
                if (j == 15 && r < 2) edgeRow[wid][rb] = prev;  // ends as tags[2047]
            }
        }
    } else {
        // ===================== BACKWARD WAVE: chunks 63..32 =====================
        stage(NCH - 1, 0);
        for (int ii = 0; ii < NCHH; ++ii) {
            const int pb = ii & 1;
            if (ii + 1 < NCHH) {
                stage(NCH - 2 - ii, pb ^ 1);
                __builtin_amdgcn_s_waitcnt(0x0F7A);  // vmcnt<=10
            } else {
                __builtin_amdgcn_s_waitcnt(0x0F70);  // vmcnt(0)
            }
            __builtin_amdgcn_sched_barrier(0);

            const float* fp = &FB[pb * FBW2 + rb * ROWW + colj];
            float fr[8];
#pragma unroll
            for (int u = 0; u < 8; ++u) fr[u] = fp[(CH - 1 - u) * 16];
            ef = exp2f(fmaf(fr[0], LOG2E, -4.0f));  // prime

            for (int tb = 0; tb < CH; tb += 8) {
                const float* fq = fp + (CH - 9 - tb) * 16;  // underrun -> slack
#pragma unroll
                for (int u = 0; u < 8; ++u) {
                    const float fn = fr[(u + 1) & 7];
                    fr[u] = fq[-(u * 16)];

                    float negc;
                    if (u == 6) {
                        const int kprev = (((__float_as_int(bp) >> 23) & 0xFF) - 127);
                        Cacc += 32 + kprev;
                        negc = -(4.0f + (float)kprev);
                    } else {
                        negc = -4.0f;
                    }

                    float part, efa;
                    MATVEC8_BWD(s, ef, part, efa, fn, negc, et);
                    const float sum = xadd32(part);

                    // lo rows: s = sum[j]; hi rows: s = sum[(j+8)]
                    float snew, efn;
                    asm("v_mov_b32 %[sv], %[sum]\n\t"
                        "v_exp_f32 %[efn], %[efa]\n\t"
                        "v_mov_b32_dpp %[sv], %[sum] row_ror:8 row_mask:0xc bank_mask:0xf"
                        : [sv] "=&v"(snew), [efn] "=&v"(efn)
                        : [sum] "v"(sum), [efa] "v"(efa));
                    s = snew;
                    ef = efn;

                    if (u == 7)
                        bp = __int_as_float(__builtin_amdgcn_ds_bpermute(
                                rowbase, __float_as_int(s)));
                }
            }

            // gold sidecar: transitions LEAVING t, next carried (chunks descending)
            {
                const int* tg = &TG[wid][pb][rb * CH];
                const int t4 = j * 4;
                const float* fbase = &FB[pb * FBW2 + rb * ROWW];
                const int nlast = (j == 15) ? edgeRow[wid][rb] : tg[t4 + 4];
#pragma unroll
                for (int q = 0; q < 4; ++q) {
                    const int tc = tg[t4 + q];
                    const int tn = (q == 3) ? nlast : tg[t4 + q + 1];
                    gold += TlS[tn * K_TAGS + tc];
                    gold += fbase[(t4 + q) * 16 + tc];
                }
                if (j == 0 && r < 2) edgeRow[wid][rb] = tg[0];  // ends as tags[2048]
            }
        }
    }

    // ---- epilogue: reduce gold over the 16-lane row, dump half-state (lo rows) ----
    float gg = gold;
#pragma unroll
    for (int dd = 1; dd < 16; dd <<= 1) gg += __shfl_xor(gg, dd, 16);

    if (r < 2) {  // lo rows hold the un-rotated state
        if (!half) {
            ws[WS_VF + b * 16 + j] = s;
            if (j == 0) {
                ((int*)ws)[WS_CF + b] = Cacc;
                const int tn = tags[(size_t)b * T_LEN + (T_LEN / 2)];
                ws[WS_GF + b] = gg + TlS[tn * K_TAGS + edgeRow[wid][rb]];
            }
        } else {
            ws[WS_VB + b * 16 + j] = s;
            if (j == 0) {
                ((int*)ws)[WS_CB + b] = Cacc;
                ws[WS_GB + b] = gg;
            }
        }
    }
}

__global__ __launch_bounds__(64) void crf_combine(
        const float* __restrict__ ws, float* __restrict__ out) {
    const int b = blockIdx.x * 64 + threadIdx.x;
    const float* vf = ws + WS_VF + b * 16;
    const float* vb = ws + WS_VB + b * 16;
    float dot = 0.0f;
#pragma unroll
    for (int t = 0; t < 16; ++t) dot = fmaf(vf[t], vb[t], dot);
    const int cf = ((const int*)ws)[WS_CF + b];
    const int cb = ((const int*)ws)[WS_CB + b];
    const float g = ws[WS_GF + b] + ws[WS_GB + b];
    out[b] = LN2 * (log2f(dot) + (float)(cf + cb)) - g;
}

extern "C" void kernel_launch(void* const* d_in, const int* in_sizes, int n_in,
                              void* d_out, int out_size, void* d_ws, size_t ws_size,
                              hipStream_t stream) {
    const float* feats = (const float*)d_in[0];
    const int* tags = (const int*)d_in[1];
    const float* trans = (const float*)d_in[2];
    float* out = (float*)d_out;
    float* ws = (float*)d_ws;

    crf_half_kernel<<<dim3(B_TOT / 4), dim3(256), 0, stream>>>(feats, tags, trans, ws);
    crf_combine<<<dim3(B_TOT / 64), dim3(64), 0, stream>>>(ws, out);
}